// Round 13
// baseline (160.899 us; speedup 1.0000x reference)
//
#include <hip/hip_runtime.h>
#include <hip/hip_bf16.h>

typedef __attribute__((ext_vector_type(4))) float f32x4;
typedef __attribute__((ext_vector_type(8))) short bf16x8;

constexpr int Bn  = 4;
constexpr int Ln  = 1024;
constexpr int Dn  = 1024;
constexpr int Hn  = 16;
constexpr int HDn = 64;

static __device__ __forceinline__ unsigned short bf16r(float f) {
    union { float f; unsigned int u; } x;
    x.f = f;
    unsigned int r = x.u + 0x7fffu + ((x.u >> 16) & 1u);
    return (unsigned short)(r >> 16);
}

static __device__ __forceinline__ unsigned int pk2(float a, float b) {
    return (unsigned int)bf16r(a) | ((unsigned int)bf16r(b) << 16);
}

// ---------------------------------------------------------------------------
// Fused prep. grid (16,16,5) x 256 threads.  (unchanged)
//  z<4 : V f32 -> Vt bf16 [B,H,hd,L] (per-head transpose via LDS).
//  z==4: W f32 -> Wbf bf16, 64x64 tile.
// ---------------------------------------------------------------------------
__global__ __launch_bounds__(256) void prep_kernel(
    const float* __restrict__ Vg, const float* __restrict__ Wg,
    unsigned short* __restrict__ Vtg, unsigned short* __restrict__ Wbf)
{
    const int tid = threadIdx.x;
    if (blockIdx.z == 4) {
        const int r0 = blockIdx.x * 64, c0 = blockIdx.y * 64;
#pragma unroll 4
        for (int i = 0; i < 4; ++i) {
            int e4 = i * 256 + tid;
            int r = e4 >> 4, c4 = e4 & 15;
            const float* p = Wg + (size_t)(r0 + r) * Dn + c0 + c4 * 4;
            float4 v = *(const float4*)p;
            ushort4 o;
            o.x = bf16r(v.x); o.y = bf16r(v.y); o.z = bf16r(v.z); o.w = bf16r(v.w);
            *(ushort4*)(Wbf + (size_t)(r0 + r) * Dn + c0 + c4 * 4) = o;
        }
        return;
    }

    __shared__ unsigned short T[64][72];   // [d][k]
    const int k0 = blockIdx.x * 64;
    const int h  = blockIdx.y;
    const int b  = blockIdx.z;
    const float* Vb = Vg + (size_t)b * Ln * Dn + h * HDn;

#pragma unroll 4
    for (int i = 0; i < 4; ++i) {
        int e4 = i * 256 + tid;
        int r = e4 >> 4, c4 = e4 & 15;
        float4 vv = *(const float4*)(Vb + (size_t)(k0 + r) * Dn + c4 * 4);
        T[c4 * 4 + 0][r] = bf16r(vv.x);
        T[c4 * 4 + 1][r] = bf16r(vv.y);
        T[c4 * 4 + 2][r] = bf16r(vv.z);
        T[c4 * 4 + 3][r] = bf16r(vv.w);
    }
    __syncthreads();
    unsigned short* out = Vtg + ((size_t)(b * Hn + h) * HDn) * Ln + k0;
#pragma unroll 2
    for (int i = 0; i < 2; ++i) {
        int e8 = i * 256 + tid;
        int r = e8 >> 3, c8 = e8 & 7;
        *(uint4*)(out + (size_t)r * Ln + c8 * 8) = *(const uint4*)&T[r][c8 * 8];
    }
}

// ---------------------------------------------------------------------------
// Flash attention, v11 = v10 (in-register P, inline-K dbuf staging, XOR
// swizzle, builtin exp2, forced unrolls) with KVBLK 64 -> 128:
//  - barriers/tile-loop halved (16 -> 8), MFMA cluster per phase doubled
//    (64/wave/tile) -> staging latency hides under 2x longer compute.
//  - LDS 32 -> 64 KB (dbuf 2x(K 16KB + V^T 16KB)); occupancy unchanged
//    (1 block/CU at grid 256 either way).
//  - QK runs in two halves reusing st[2][4] to cap VGPR (<256, 2 waves/SIMD).
//  - in-reg P generalizes: apk[hf][kk], kk=0..3, same key permutation
//    key(kk, quad, j) = kk*32 + (j>>2)*16 + quad*4 + (j&3) on BOTH operands.
// ---------------------------------------------------------------------------
__global__ __launch_bounds__(512) void attn_kernel(
    const float* __restrict__ Qg, const float* __restrict__ Kg,
    const unsigned short* __restrict__ Vtg, unsigned short* __restrict__ Xg)
{
    __shared__ uint4 Ks4[2][128][8];    // 32 KB (dbuf, swizzled cols)
    __shared__ uint4 Vts4[2][64][16];   // 32 KB [d][k], swizzled (low 3 bits)

    const int tid  = threadIdx.x;
    const int wave = tid >> 6;     // 0..7
    const int lane = tid & 63;
    const int l16  = lane & 15;
    const int quad = lane >> 4;
    const int r7   = l16 & 7;      // swizzle key
    const int wb   = wave * 32;

    // XCD-aware decode: flat = xcd + 8*(qt + 4*gg); bh = xcd + 8*gg.
    const int flat = blockIdx.x;
    const int xcd  = flat & 7;
    const int j    = flat >> 3;
    const int qt   = j & 3;
    const int gg   = j >> 2;
    const int g    = xcd + 8 * gg;   // 0..63
    const int h    = g & 15;
    const int b    = g >> 4;
    const int q0   = qt * 256;

    const float* Kf   = Kg + (size_t)b * Ln * Dn + h * HDn;               // f32
    const uint4* Vtb4 = (const uint4*)(Vtg + ((size_t)(b * Hn + h) * HDn) * Ln);

    // Q fragments (read exactly once). B-operand layout: n=l16, k=quad*8+j.
    bf16x8 bq[2][2];
#pragma unroll 2
    for (int hf = 0; hf < 2; ++hf) {
        const float* qp = Qg + ((size_t)b * Ln + q0 + wb + hf * 16 + l16) * Dn
                             + h * HDn + quad * 8;
        float4 a0 = *(const float4*)qp;
        float4 a1 = *(const float4*)(qp + 4);
        float4 a2 = *(const float4*)(qp + 32);
        float4 a3 = *(const float4*)(qp + 36);
        bq[hf][0][0] = (short)bf16r(a0.x); bq[hf][0][1] = (short)bf16r(a0.y);
        bq[hf][0][2] = (short)bf16r(a0.z); bq[hf][0][3] = (short)bf16r(a0.w);
        bq[hf][0][4] = (short)bf16r(a1.x); bq[hf][0][5] = (short)bf16r(a1.y);
        bq[hf][0][6] = (short)bf16r(a1.z); bq[hf][0][7] = (short)bf16r(a1.w);
        bq[hf][1][0] = (short)bf16r(a2.x); bq[hf][1][1] = (short)bf16r(a2.y);
        bq[hf][1][2] = (short)bf16r(a2.z); bq[hf][1][3] = (short)bf16r(a2.w);
        bq[hf][1][4] = (short)bf16r(a3.x); bq[hf][1][5] = (short)bf16r(a3.y);
        bq[hf][1][6] = (short)bf16r(a3.z); bq[hf][1][7] = (short)bf16r(a3.w);
    }

    const float SC = 1.4426950408889634f / 32.0f;   // log2(e)/sqrt(D)

    float lsum[2] = {0.f, 0.f};
    f32x4 Oacc[2][4];
#pragma unroll 2
    for (int hf = 0; hf < 2; ++hf)
#pragma unroll 4
        for (int d = 0; d < 4; ++d) Oacc[hf][d] = (f32x4){0.f, 0.f, 0.f, 0.f};

    // Staging: 512 threads, 2 elements each per array per 128-key tile.
    //  K: e = i*512+tid -> row e>>3 (0..127), col e&7   (uint4, f32 src x2)
    //  V: e           -> row e>>4 (0..63),  col e&15    (uint4)
    float4 kr[2][2];
    uint4  vr[2];

    // Prologue: tile 0 -> buf 0 (direct convert-write); issue tile-1 loads.
#pragma unroll 2
    for (int i = 0; i < 2; ++i) {
        int e = i * 512 + tid;
        int srk = e >> 3, sck = e & 7;
        float4 k0v = *(const float4*)(Kf + (size_t)srk * Dn + sck * 8);
        float4 k1v = *(const float4*)(Kf + (size_t)srk * Dn + sck * 8 + 4);
        Ks4[0][srk][sck ^ (srk & 7)] =
            (uint4){pk2(k0v.x, k0v.y), pk2(k0v.z, k0v.w),
                    pk2(k1v.x, k1v.y), pk2(k1v.z, k1v.w)};
        int srv = e >> 4, scv = e & 15;
        Vts4[0][srv][scv ^ (srv & 7)] = Vtb4[(size_t)srv * 128 + scv];
    }
#pragma unroll 2
    for (int i = 0; i < 2; ++i) {
        int e = i * 512 + tid;
        int srk = e >> 3, sck = e & 7;
        kr[i][0] = *(const float4*)(Kf + (size_t)(128 + srk) * Dn + sck * 8);
        kr[i][1] = *(const float4*)(Kf + (size_t)(128 + srk) * Dn + sck * 8 + 4);
        int srv = e >> 4, scv = e & 15;
        vr[i] = Vtb4[(size_t)srv * 128 + 16 + scv];
    }
    __syncthreads();

    constexpr int NT = Ln / 128;   // 8
    for (int it = 0; it < NT; ++it) {
        const int cur = it & 1;

        // S^T = K Q^T over 128 keys, two halves (st[2][4] reused).
        uint4 apk[2][4];
#pragma unroll 2
        for (int half = 0; half < 2; ++half) {
            f32x4 st[2][4];
            __builtin_amdgcn_s_setprio(1);
#pragma unroll 4
            for (int n = 0; n < 4; ++n) {
                int row = half * 64 + n * 16 + l16;
                bf16x8 a0 = __builtin_bit_cast(bf16x8, Ks4[cur][row][quad ^ r7]);
                bf16x8 a1 = __builtin_bit_cast(bf16x8, Ks4[cur][row][(4 + quad) ^ r7]);
#pragma unroll 2
                for (int hf = 0; hf < 2; ++hf) {
                    f32x4 acc = (f32x4){0.f, 0.f, 0.f, 0.f};
                    acc = __builtin_amdgcn_mfma_f32_16x16x32_bf16(a0, bq[hf][0], acc, 0, 0, 0);
                    acc = __builtin_amdgcn_mfma_f32_16x16x32_bf16(a1, bq[hf][1], acc, 0, 0, 0);
                    st[hf][n] = acc;
                }
            }
            __builtin_amdgcn_s_setprio(0);

            // P = exp2(S^T*SC) packed straight into PV A-frags (no LDS).
#pragma unroll 2
            for (int hf = 0; hf < 2; ++hf) {
                float ls = 0.f;
#pragma unroll 4
                for (int n = 0; n < 4; ++n) {
                    float p0 = __builtin_amdgcn_exp2f(st[hf][n][0] * SC);
                    float p1 = __builtin_amdgcn_exp2f(st[hf][n][1] * SC);
                    float p2 = __builtin_amdgcn_exp2f(st[hf][n][2] * SC);
                    float p3 = __builtin_amdgcn_exp2f(st[hf][n][3] * SC);
                    ls += (p0 + p1) + (p2 + p3);
                    unsigned int wx = pk2(p0, p1);
                    unsigned int wy = pk2(p2, p3);
                    int kk = half * 2 + (n >> 1);
                    if (n & 1) { apk[hf][kk].z = wx; apk[hf][kk].w = wy; }
                    else       { apk[hf][kk].x = wx; apk[hf][kk].y = wy; }
                }
                lsum[hf] += ls;
            }
        }

        // O += P V with the permuted key order (4 kk blocks of 32 keys).
        __builtin_amdgcn_s_setprio(1);
#pragma unroll 4
        for (int kk = 0; kk < 4; ++kk) {
            const int b1 = 4 * kk + (quad >> 1);
            bf16x8 bv[4];
#pragma unroll 4
            for (int dt = 0; dt < 4; ++dt) {
                const uint2* vp = (const uint2*)&Vts4[cur][dt * 16 + l16][0];
                uint2 c1 = vp[(((b1)     ^ r7) << 1) + (quad & 1)];
                uint2 c2 = vp[(((b1 + 2) ^ r7) << 1) + (quad & 1)];
                bv[dt] = __builtin_bit_cast(bf16x8, (uint4){c1.x, c1.y, c2.x, c2.y});
            }
#pragma unroll 2
            for (int hf = 0; hf < 2; ++hf) {
                bf16x8 ap = __builtin_bit_cast(bf16x8, apk[hf][kk]);
#pragma unroll 4
                for (int dt = 0; dt < 4; ++dt)
                    Oacc[hf][dt] = __builtin_amdgcn_mfma_f32_16x16x32_bf16(
                        ap, bv[dt], Oacc[hf][dt], 0, 0, 0);
            }
        }
        __builtin_amdgcn_s_setprio(0);

        // Stage tile it+1 into the other buffer; issue loads for tile it+2.
        if (it + 1 < NT) {
#pragma unroll 2
            for (int i = 0; i < 2; ++i) {
                int e = i * 512 + tid;
                int srk = e >> 3, sck = e & 7;
                Ks4[cur ^ 1][srk][sck ^ (srk & 7)] =
                    (uint4){pk2(kr[i][0].x, kr[i][0].y), pk2(kr[i][0].z, kr[i][0].w),
                            pk2(kr[i][1].x, kr[i][1].y), pk2(kr[i][1].z, kr[i][1].w)};
                int srv = e >> 4, scv = e & 15;
                Vts4[cur ^ 1][srv][scv ^ (srv & 7)] = vr[i];
            }
            if (it + 2 < NT) {
#pragma unroll 2
                for (int i = 0; i < 2; ++i) {
                    int e = i * 512 + tid;
                    int srk = e >> 3, sck = e & 7;
                    kr[i][0] = *(const float4*)(Kf + (size_t)((it + 2) * 128 + srk) * Dn + sck * 8);
                    kr[i][1] = *(const float4*)(Kf + (size_t)((it + 2) * 128 + srk) * Dn + sck * 8 + 4);
                    int srv = e >> 4, scv = e & 15;
                    vr[i] = Vtb4[(size_t)srv * 128 + (it + 2) * 16 + scv];
                }
            }
        }
        __syncthreads();
    }

    // Row sums live per-lane (q=l16); reduce across quads.
    float inv[2];
#pragma unroll 2
    for (int hf = 0; hf < 2; ++hf) {
        float rs = lsum[hf];
        rs += __shfl_xor(rs, 16, 64);
        rs += __shfl_xor(rs, 32, 64);
        inv[hf] = __builtin_amdgcn_rcpf(rs);
    }

    unsigned short* Xb = Xg + ((size_t)b * Ln + q0 + wb) * Dn + h * HDn;
#pragma unroll 2
    for (int hf = 0; hf < 2; ++hf)
#pragma unroll 4
        for (int r = 0; r < 4; ++r) {
            float iv = __shfl(inv[hf], quad * 4 + r, 64);
            int row = hf * 16 + quad * 4 + r;
#pragma unroll 4
            for (int dt = 0; dt < 4; ++dt)
                Xb[(size_t)row * Dn + dt * 16 + l16] = bf16r(Oacc[hf][dt][r] * iv);
        }
}

// ---------------------------------------------------------------------------
// Projection v3: 2-phase double-buffered (unchanged from round 11).
// ---------------------------------------------------------------------------
__global__ __launch_bounds__(256) void proj_kernel(
    const unsigned short* __restrict__ Xg, const unsigned short* __restrict__ Wbf,
    const float* __restrict__ bg, float* __restrict__ Yg)
{
    __shared__ unsigned short XsL[2][64 * 64];   // 2 x 8 KB
    __shared__ unsigned short WsL[2][64 * 64];   // 2 x 8 KB

    const int tid  = threadIdx.x;
    const int wave = tid >> 6;
    const int lane = tid & 63;
    const int l16  = lane & 15;
    const int quad = lane >> 4;
    const int mw   = (wave & 1) * 32;
    const int nw   = (wave >> 1) * 32;

    const int m0 = blockIdx.x * 64;
    const int n0 = blockIdx.y * 64;

    f32x4 acc[2][2];
#pragma unroll 2
    for (int mt = 0; mt < 2; ++mt)
#pragma unroll 2
        for (int nt = 0; nt < 2; ++nt)
            acc[mt][nt] = (f32x4){0.f, 0.f, 0.f, 0.f};

    // Prologue: stage tile 0 into buf 0; barrier drains it.
#pragma unroll 2
    for (int i = 0; i < 2; ++i) {
        int fl = i * 256 + tid;            // 512 x 16B = 8 KB each
        int r = fl >> 3, c8 = fl & 7;
        __builtin_amdgcn_global_load_lds(
            (const __attribute__((address_space(1))) void*)
                (Xg + (size_t)(m0 + r) * Dn + c8 * 8),
            (__attribute__((address_space(3))) void*)&XsL[0][fl * 8], 16, 0, 0);
        __builtin_amdgcn_global_load_lds(
            (const __attribute__((address_space(1))) void*)
                (Wbf + (size_t)(n0 + r) * Dn + c8 * 8),
            (__attribute__((address_space(3))) void*)&WsL[0][fl * 8], 16, 0, 0);
    }
    __syncthreads();

    constexpr int NI = Dn / 64;   // 16
    for (int it = 0; it < NI; ++it) {
        const int cur = it & 1;

        if (it + 1 < NI) {
            const int kk1 = (it + 1) * 64;
#pragma unroll 2
            for (int i = 0; i < 2; ++i) {
                int fl = i * 256 + tid;
                int r = fl >> 3, c8 = fl & 7;
                __builtin_amdgcn_global_load_lds(
                    (const __attribute__((address_space(1))) void*)
                        (Xg + (size_t)(m0 + r) * Dn + kk1 + c8 * 8),
                    (__attribute__((address_space(3))) void*)&XsL[cur ^ 1][fl * 8],
                    16, 0, 0);
                __builtin_amdgcn_global_load_lds(
                    (const __attribute__((address_space(1))) void*)
                        (Wbf + (size_t)(n0 + r) * Dn + kk1 + c8 * 8),
                    (__attribute__((address_space(3))) void*)&WsL[cur ^ 1][fl * 8],
                    16, 0, 0);
            }
        }

        __builtin_amdgcn_s_setprio(1);
#pragma unroll 2
        for (int ks = 0; ks < 2; ++ks) {
            bf16x8 af[2], bfr[2];
#pragma unroll 2
            for (int mt = 0; mt < 2; ++mt)
                af[mt] = *(const bf16x8*)&XsL[cur][(mw + mt * 16 + l16) * 64
                                                  + ks * 32 + quad * 8];
#pragma unroll 2
            for (int nt = 0; nt < 2; ++nt)
                bfr[nt] = *(const bf16x8*)&WsL[cur][(nw + nt * 16 + l16) * 64
                                                   + ks * 32 + quad * 8];
#pragma unroll 2
            for (int mt = 0; mt < 2; ++mt)
#pragma unroll 2
                for (int nt = 0; nt < 2; ++nt)
                    acc[mt][nt] = __builtin_amdgcn_mfma_f32_16x16x32_bf16(
                        af[mt], bfr[nt], acc[mt][nt], 0, 0, 0);
        }
        __builtin_amdgcn_s_setprio(0);

        __syncthreads();   // drains vmcnt (next tile resident) + reads done
    }

#pragma unroll 2
    for (int nt = 0; nt < 2; ++nt) {
        int col = n0 + nw + nt * 16 + l16;
        float bb = bg[col];
#pragma unroll 2
        for (int mt = 0; mt < 2; ++mt)
#pragma unroll 4
            for (int r = 0; r < 4; ++r) {
                int row = m0 + mw + mt * 16 + quad * 4 + r;
                Yg[(size_t)row * Dn + col] = acc[mt][nt][r] + bb;
            }
    }
}

extern "C" void kernel_launch(void* const* d_in, const int* in_sizes, int n_in,
                              void* d_out, int out_size, void* d_ws, size_t ws_size,
                              hipStream_t stream) {
    const float* Q    = (const float*)d_in[0];
    const float* K    = (const float*)d_in[1];
    const float* V    = (const float*)d_in[2];
    const float* W    = (const float*)d_in[3];
    const float* bias = (const float*)d_in[4];

    unsigned short* Vt  = (unsigned short*)d_ws;                  // 8 MB
    unsigned short* Wbf = Vt + (size_t)Bn * Ln * Dn;              // 2 MB
    unsigned short* X   = Wbf + (size_t)Dn * Dn;                  // 8 MB
    float* Y = (float*)d_out;

    dim3 gp(Ln / 64, Hn, Bn + 1);        // z=0..3: V prep; z=4: W prep
    prep_kernel<<<gp, 256, 0, stream>>>(V, W, Vt, Wbf);

    attn_kernel<<<dim3(256, 1, 1), 512, 0, stream>>>(Q, K, Vt, X);

    dim3 g2(Bn * Ln / 64, Dn / 64);      // 64 x 16 = 1024 blocks
    proj_kernel<<<g2, 256, 0, stream>>>(X, Wbf, bias, Y);
}

// Round 14
// 147.714 us; speedup vs baseline: 1.0893x; 1.0893x over previous
//
#include <hip/hip_runtime.h>
#include <hip/hip_bf16.h>

typedef __attribute__((ext_vector_type(4))) float f32x4;
typedef __attribute__((ext_vector_type(8))) short bf16x8;

constexpr int Bn  = 4;
constexpr int Ln  = 1024;
constexpr int Dn  = 1024;
constexpr int Hn  = 16;
constexpr int HDn = 64;

static __device__ __forceinline__ unsigned short bf16r(float f) {
    union { float f; unsigned int u; } x;
    x.f = f;
    unsigned int r = x.u + 0x7fffu + ((x.u >> 16) & 1u);
    return (unsigned short)(r >> 16);
}

static __device__ __forceinline__ unsigned int pk2(float a, float b) {
    return (unsigned int)bf16r(a) | ((unsigned int)bf16r(b) << 16);
}

// ---------------------------------------------------------------------------
// Fused prep. grid (16,16,5) x 256 threads.
//  z<4 : V f32 -> Vt bf16 [B,H,hd,L] (per-head transpose via LDS).
//  z==4: W f32 -> Wbf bf16, 64x64 tile.
// ---------------------------------------------------------------------------
__global__ __launch_bounds__(256) void prep_kernel(
    const float* __restrict__ Vg, const float* __restrict__ Wg,
    unsigned short* __restrict__ Vtg, unsigned short* __restrict__ Wbf)
{
    const int tid = threadIdx.x;
    if (blockIdx.z == 4) {
        const int r0 = blockIdx.x * 64, c0 = blockIdx.y * 64;
#pragma unroll 4
        for (int i = 0; i < 4; ++i) {
            int e4 = i * 256 + tid;
            int r = e4 >> 4, c4 = e4 & 15;
            const float* p = Wg + (size_t)(r0 + r) * Dn + c0 + c4 * 4;
            float4 v = *(const float4*)p;
            ushort4 o;
            o.x = bf16r(v.x); o.y = bf16r(v.y); o.z = bf16r(v.z); o.w = bf16r(v.w);
            *(ushort4*)(Wbf + (size_t)(r0 + r) * Dn + c0 + c4 * 4) = o;
        }
        return;
    }

    __shared__ unsigned short T[64][72];   // [d][k]
    const int k0 = blockIdx.x * 64;
    const int h  = blockIdx.y;
    const int b  = blockIdx.z;
    const float* Vb = Vg + (size_t)b * Ln * Dn + h * HDn;

#pragma unroll 4
    for (int i = 0; i < 4; ++i) {
        int e4 = i * 256 + tid;
        int r = e4 >> 4, c4 = e4 & 15;
        float4 vv = *(const float4*)(Vb + (size_t)(k0 + r) * Dn + c4 * 4);
        T[c4 * 4 + 0][r] = bf16r(vv.x);
        T[c4 * 4 + 1][r] = bf16r(vv.y);
        T[c4 * 4 + 2][r] = bf16r(vv.z);
        T[c4 * 4 + 3][r] = bf16r(vv.w);
    }
    __syncthreads();
    unsigned short* out = Vtg + ((size_t)(b * Hn + h) * HDn) * Ln + k0;
#pragma unroll 2
    for (int i = 0; i < 2; ++i) {
        int e8 = i * 256 + tid;
        int r = e8 >> 3, c8 = e8 & 7;
        *(uint4*)(out + (size_t)r * Ln + c8 * 8) = *(const uint4*)&T[r][c8 * 8];
    }
}

// ---------------------------------------------------------------------------
// Flash attention, v10 (REVERTED from the KVBLK=128 v11, which regressed to
// 62us: 80KB LDS + 112 VGPR killed wave headroom). v10 = 512 thr, q-tile
// 256, grid 256, KVBLK 64, single-barrier dbuf K/V staging (K inline
// f32->bf16 at the LDS-write point), XOR swizzle, builtin exp2, forced
// unrolls, IN-REGISTER P:
//   key(quad*8+j) = kk*32 + (j>>2)*16 + quad*4 + (j&3) applied to BOTH PV
//   operands makes the S^T output registers the PV A-fragment directly --
//   no P LDS array, no round-trip. V B-frags = two uint2 reads (same bytes).
// ---------------------------------------------------------------------------
__global__ __launch_bounds__(512) void attn_kernel(
    const float* __restrict__ Qg, const float* __restrict__ Kg,
    const unsigned short* __restrict__ Vtg, unsigned short* __restrict__ Xg)
{
    __shared__ uint4 Ks4[2][64][8];    // 16 KB  (dbuf, swizzled cols)
    __shared__ uint4 Vts4[2][64][8];   // 16 KB  [d][k]

    const int tid  = threadIdx.x;
    const int wave = tid >> 6;     // 0..7
    const int lane = tid & 63;
    const int l16  = lane & 15;
    const int quad = lane >> 4;
    const int r7   = l16 & 7;      // swizzle key
    const int wb   = wave * 32;

    // XCD-aware decode: flat = xcd + 8*(qt + 4*gg); bh = xcd + 8*gg.
    const int flat = blockIdx.x;
    const int xcd  = flat & 7;
    const int j    = flat >> 3;
    const int qt   = j & 3;
    const int gg   = j >> 2;
    const int g    = xcd + 8 * gg;   // 0..63
    const int h    = g & 15;
    const int b    = g >> 4;
    const int q0   = qt * 256;

    const float* Kf   = Kg + (size_t)b * Ln * Dn + h * HDn;               // f32
    const uint4* Vtb4 = (const uint4*)(Vtg + ((size_t)(b * Hn + h) * HDn) * Ln);

    // Q fragments (read exactly once). B-operand layout: n=l16, k=quad*8+j.
    bf16x8 bq[2][2];
#pragma unroll 2
    for (int hf = 0; hf < 2; ++hf) {
        const float* qp = Qg + ((size_t)b * Ln + q0 + wb + hf * 16 + l16) * Dn
                             + h * HDn + quad * 8;
        float4 a0 = *(const float4*)qp;
        float4 a1 = *(const float4*)(qp + 4);
        float4 a2 = *(const float4*)(qp + 32);
        float4 a3 = *(const float4*)(qp + 36);
        bq[hf][0][0] = (short)bf16r(a0.x); bq[hf][0][1] = (short)bf16r(a0.y);
        bq[hf][0][2] = (short)bf16r(a0.z); bq[hf][0][3] = (short)bf16r(a0.w);
        bq[hf][0][4] = (short)bf16r(a1.x); bq[hf][0][5] = (short)bf16r(a1.y);
        bq[hf][0][6] = (short)bf16r(a1.z); bq[hf][0][7] = (short)bf16r(a1.w);
        bq[hf][1][0] = (short)bf16r(a2.x); bq[hf][1][1] = (short)bf16r(a2.y);
        bq[hf][1][2] = (short)bf16r(a2.z); bq[hf][1][3] = (short)bf16r(a2.w);
        bq[hf][1][4] = (short)bf16r(a3.x); bq[hf][1][5] = (short)bf16r(a3.y);
        bq[hf][1][6] = (short)bf16r(a3.z); bq[hf][1][7] = (short)bf16r(a3.w);
    }

    const float SC = 1.4426950408889634f / 32.0f;   // log2(e)/sqrt(D)

    float lsum[2] = {0.f, 0.f};
    f32x4 Oacc[2][4];
#pragma unroll 2
    for (int hf = 0; hf < 2; ++hf)
#pragma unroll 4
        for (int d = 0; d < 4; ++d) Oacc[hf][d] = (f32x4){0.f, 0.f, 0.f, 0.f};

    // Staging: 512 threads; K = 2 raw float4 (converted at write), V = uint4.
    const int sr = tid >> 3, sc = tid & 7;
    const int scs = sc ^ (sr & 7);           // swizzled column
    float4 kr0, kr1;
    uint4 vreg;

    // Prologue: tile 0 -> buf 0; issue tile-1 loads; one barrier.
    kr0 = *(const float4*)(Kf + (size_t)sr * Dn + sc * 8);
    kr1 = *(const float4*)(Kf + (size_t)sr * Dn + sc * 8 + 4);
    vreg = Vtb4[(size_t)sr * 128 + sc];
    Ks4[0][sr][scs] = (uint4){pk2(kr0.x, kr0.y), pk2(kr0.z, kr0.w),
                              pk2(kr1.x, kr1.y), pk2(kr1.z, kr1.w)};
    Vts4[0][sr][scs] = vreg;
    kr0 = *(const float4*)(Kf + (size_t)(64 + sr) * Dn + sc * 8);
    kr1 = *(const float4*)(Kf + (size_t)(64 + sr) * Dn + sc * 8 + 4);
    vreg = Vtb4[(size_t)sr * 128 + 8 + sc];
    __syncthreads();

    constexpr int NT = Ln / 64;
    for (int it = 0; it < NT; ++it) {
        const int cur = it & 1;

        // S^T = K Q^T : A = K-frag (m=key), B = Q-frag (n=q). 8 reads, 16 MFMA.
        f32x4 st[2][4];
        __builtin_amdgcn_s_setprio(1);
#pragma unroll 4
        for (int n = 0; n < 4; ++n) {
            bf16x8 a0 = __builtin_bit_cast(bf16x8, Ks4[cur][n * 16 + l16][quad ^ r7]);
            bf16x8 a1 = __builtin_bit_cast(bf16x8, Ks4[cur][n * 16 + l16][(4 + quad) ^ r7]);
#pragma unroll 2
            for (int hf = 0; hf < 2; ++hf) {
                f32x4 acc = (f32x4){0.f, 0.f, 0.f, 0.f};
                acc = __builtin_amdgcn_mfma_f32_16x16x32_bf16(a0, bq[hf][0], acc, 0, 0, 0);
                acc = __builtin_amdgcn_mfma_f32_16x16x32_bf16(a1, bq[hf][1], acc, 0, 0, 0);
                st[hf][n] = acc;
            }
        }
        __builtin_amdgcn_s_setprio(0);

        // P = exp2(S^T * SC) packed straight into PV A-fragments (no LDS).
        // apk[hf][kk] elems j: key = kk*32 + (j>>2)*16 + quad*4 + (j&3).
        uint4 apk[2][2];
#pragma unroll 2
        for (int hf = 0; hf < 2; ++hf) {
            float ls = 0.f;
#pragma unroll 4
            for (int n = 0; n < 4; ++n) {
                float p0 = __builtin_amdgcn_exp2f(st[hf][n][0] * SC);
                float p1 = __builtin_amdgcn_exp2f(st[hf][n][1] * SC);
                float p2 = __builtin_amdgcn_exp2f(st[hf][n][2] * SC);
                float p3 = __builtin_amdgcn_exp2f(st[hf][n][3] * SC);
                ls += (p0 + p1) + (p2 + p3);
                unsigned int wx = pk2(p0, p1);
                unsigned int wy = pk2(p2, p3);
                if (n & 1) { apk[hf][n >> 1].z = wx; apk[hf][n >> 1].w = wy; }
                else       { apk[hf][n >> 1].x = wx; apk[hf][n >> 1].y = wy; }
            }
            lsum[hf] += ls;
        }

        // O += P V with the permuted key order. B-frag = two uint2 reads
        // at key offsets quad*4 and 16+quad*4 within each kk*32 block.
        __builtin_amdgcn_s_setprio(1);
#pragma unroll 2
        for (int kk = 0; kk < 2; ++kk) {
            const int b1 = 4 * kk + (quad >> 1);
            bf16x8 bv[4];
#pragma unroll 4
            for (int dt = 0; dt < 4; ++dt) {
                const uint2* vp = (const uint2*)&Vts4[cur][dt * 16 + l16][0];
                uint2 c1 = vp[(((b1)     ^ r7) << 1) + (quad & 1)];
                uint2 c2 = vp[(((b1 + 2) ^ r7) << 1) + (quad & 1)];
                bv[dt] = __builtin_bit_cast(bf16x8, (uint4){c1.x, c1.y, c2.x, c2.y});
            }
#pragma unroll 2
            for (int hf = 0; hf < 2; ++hf) {
                bf16x8 ap = __builtin_bit_cast(bf16x8, apk[hf][kk]);
#pragma unroll 4
                for (int dt = 0; dt < 4; ++dt)
                    Oacc[hf][dt] = __builtin_amdgcn_mfma_f32_16x16x32_bf16(
                        ap, bv[dt], Oacc[hf][dt], 0, 0, 0);
            }
        }
        __builtin_amdgcn_s_setprio(0);

        // Stage tile it+1 into the other buffer (overlaps other waves'
        // compute); issue loads for tile it+2. ONE barrier per tile.
        if (it + 1 < NT) {
            Ks4[cur ^ 1][sr][scs] = (uint4){pk2(kr0.x, kr0.y), pk2(kr0.z, kr0.w),
                                            pk2(kr1.x, kr1.y), pk2(kr1.z, kr1.w)};
            Vts4[cur ^ 1][sr][scs] = vreg;
            if (it + 2 < NT) {
                kr0 = *(const float4*)(Kf + (size_t)((it + 2) * 64 + sr) * Dn + sc * 8);
                kr1 = *(const float4*)(Kf + (size_t)((it + 2) * 64 + sr) * Dn + sc * 8 + 4);
                vreg = Vtb4[(size_t)sr * 128 + (it + 2) * 8 + sc];
            }
        }
        __syncthreads();
    }

    // Row sums live per-lane (q=l16); reduce across quads.
    float inv[2];
#pragma unroll 2
    for (int hf = 0; hf < 2; ++hf) {
        float rs = lsum[hf];
        rs += __shfl_xor(rs, 16, 64);
        rs += __shfl_xor(rs, 32, 64);
        inv[hf] = __builtin_amdgcn_rcpf(rs);
    }

    unsigned short* Xb = Xg + ((size_t)b * Ln + q0 + wb) * Dn + h * HDn;
#pragma unroll 2
    for (int hf = 0; hf < 2; ++hf)
#pragma unroll 4
        for (int r = 0; r < 4; ++r) {
            float iv = __shfl(inv[hf], quad * 4 + r, 64);
            int row = hf * 16 + quad * 4 + r;
#pragma unroll 4
            for (int dt = 0; dt < 4; ++dt)
                Xb[(size_t)row * Dn + dt * 16 + l16] = bf16r(Oacc[hf][dt][r] * iv);
        }
}

// ---------------------------------------------------------------------------
// Projection v3: 2-phase double-buffered (best measured).
// ---------------------------------------------------------------------------
__global__ __launch_bounds__(256) void proj_kernel(
    const unsigned short* __restrict__ Xg, const unsigned short* __restrict__ Wbf,
    const float* __restrict__ bg, float* __restrict__ Yg)
{
    __shared__ unsigned short XsL[2][64 * 64];   // 2 x 8 KB
    __shared__ unsigned short WsL[2][64 * 64];   // 2 x 8 KB

    const int tid  = threadIdx.x;
    const int wave = tid >> 6;
    const int lane = tid & 63;
    const int l16  = lane & 15;
    const int quad = lane >> 4;
    const int mw   = (wave & 1) * 32;
    const int nw   = (wave >> 1) * 32;

    const int m0 = blockIdx.x * 64;
    const int n0 = blockIdx.y * 64;

    f32x4 acc[2][2];
#pragma unroll 2
    for (int mt = 0; mt < 2; ++mt)
#pragma unroll 2
        for (int nt = 0; nt < 2; ++nt)
            acc[mt][nt] = (f32x4){0.f, 0.f, 0.f, 0.f};

    // Prologue: stage tile 0 into buf 0; barrier drains it.
#pragma unroll 2
    for (int i = 0; i < 2; ++i) {
        int fl = i * 256 + tid;            // 512 x 16B = 8 KB each
        int r = fl >> 3, c8 = fl & 7;
        __builtin_amdgcn_global_load_lds(
            (const __attribute__((address_space(1))) void*)
                (Xg + (size_t)(m0 + r) * Dn + c8 * 8),
            (__attribute__((address_space(3))) void*)&XsL[0][fl * 8], 16, 0, 0);
        __builtin_amdgcn_global_load_lds(
            (const __attribute__((address_space(1))) void*)
                (Wbf + (size_t)(n0 + r) * Dn + c8 * 8),
            (__attribute__((address_space(3))) void*)&WsL[0][fl * 8], 16, 0, 0);
    }
    __syncthreads();

    constexpr int NI = Dn / 64;   // 16
    for (int it = 0; it < NI; ++it) {
        const int cur = it & 1;

        if (it + 1 < NI) {
            const int kk1 = (it + 1) * 64;
#pragma unroll 2
            for (int i = 0; i < 2; ++i) {
                int fl = i * 256 + tid;
                int r = fl >> 3, c8 = fl & 7;
                __builtin_amdgcn_global_load_lds(
                    (const __attribute__((address_space(1))) void*)
                        (Xg + (size_t)(m0 + r) * Dn + kk1 + c8 * 8),
                    (__attribute__((address_space(3))) void*)&XsL[cur ^ 1][fl * 8],
                    16, 0, 0);
                __builtin_amdgcn_global_load_lds(
                    (const __attribute__((address_space(1))) void*)
                        (Wbf + (size_t)(n0 + r) * Dn + kk1 + c8 * 8),
                    (__attribute__((address_space(3))) void*)&WsL[cur ^ 1][fl * 8],
                    16, 0, 0);
            }
        }

        __builtin_amdgcn_s_setprio(1);
#pragma unroll 2
        for (int ks = 0; ks < 2; ++ks) {
            bf16x8 af[2], bfr[2];
#pragma unroll 2
            for (int mt = 0; mt < 2; ++mt)
                af[mt] = *(const bf16x8*)&XsL[cur][(mw + mt * 16 + l16) * 64
                                                  + ks * 32 + quad * 8];
#pragma unroll 2
            for (int nt = 0; nt < 2; ++nt)
                bfr[nt] = *(const bf16x8*)&WsL[cur][(nw + nt * 16 + l16) * 64
                                                   + ks * 32 + quad * 8];
#pragma unroll 2
            for (int mt = 0; mt < 2; ++mt)
#pragma unroll 2
                for (int nt = 0; nt < 2; ++nt)
                    acc[mt][nt] = __builtin_amdgcn_mfma_f32_16x16x32_bf16(
                        af[mt], bfr[nt], acc[mt][nt], 0, 0, 0);
        }
        __builtin_amdgcn_s_setprio(0);

        __syncthreads();   // drains vmcnt (next tile resident) + reads done
    }

#pragma unroll 2
    for (int nt = 0; nt < 2; ++nt) {
        int col = n0 + nw + nt * 16 + l16;
        float bb = bg[col];
#pragma unroll 2
        for (int mt = 0; mt < 2; ++mt)
#pragma unroll 4
            for (int r = 0; r < 4; ++r) {
                int row = m0 + mw + mt * 16 + quad * 4 + r;
                Yg[(size_t)row * Dn + col] = acc[mt][nt][r] + bb;
            }
    }
}

extern "C" void kernel_launch(void* const* d_in, const int* in_sizes, int n_in,
                              void* d_out, int out_size, void* d_ws, size_t ws_size,
                              hipStream_t stream) {
    const float* Q    = (const float*)d_in[0];
    const float* K    = (const float*)d_in[1];
    const float* V    = (const float*)d_in[2];
    const float* W    = (const float*)d_in[3];
    const float* bias = (const float*)d_in[4];

    unsigned short* Vt  = (unsigned short*)d_ws;                  // 8 MB
    unsigned short* Wbf = Vt + (size_t)Bn * Ln * Dn;              // 2 MB
    unsigned short* X   = Wbf + (size_t)Dn * Dn;                  // 8 MB
    float* Y = (float*)d_out;

    dim3 gp(Ln / 64, Hn, Bn + 1);        // z=0..3: V prep; z=4: W prep
    prep_kernel<<<gp, 256, 0, stream>>>(V, W, Vt, Wbf);

    attn_kernel<<<dim3(256, 1, 1), 512, 0, stream>>>(Q, K, Vt, X);

    dim3 g2(Bn * Ln / 64, Dn / 64);      // 64 x 16 = 1024 blocks
    proj_kernel<<<g2, 256, 0, stream>>>(X, Wbf, bias, Y);
}